// Round 11
// baseline (666.200 us; speedup 1.0000x reference)
//
#include <hip/hip_runtime.h>
#include <stdint.h>

// N=16, M=4, D=32, K=256, H=64, W=64 ; P = 262144 pixels
// outputs (concat, read back as f32): sample (P*256), code (P, as float), logit (P*256)
// Single fused kernel: block = 256 threads = 256 codebook rows; 128 pixels/block.

#define TINY_F 1.17549435082228750797e-38f
#define LN2F   0.69314718055994530942f
#define MARGIN 2.0e-4f

constexpr int KK  = 256;
constexpr int DD  = 32;
constexpr int PPB = 128;   // pixels per block -> grid 2048 = 8 blocks/CU exactly
constexpr int GRP = 4;     // pixels per reduce batch

// XLA:CPU vectorized log (validated R2, code absmax == 0). Rare path only.
__device__ __forceinline__ float plog_xla(float xin) {
  #pragma clang fp contract(off)
  uint32_t ix = __float_as_uint(xin);
  int e_i = (int)(ix >> 23) - 126;
  float x = __uint_as_float((ix & 0x007FFFFFu) | 0x3F000000u);
  float e = (float)e_i;
  bool lt = x < 0.707106781186547524f;
  float tmp = lt ? x : 0.0f;
  x = x - 1.0f;
  e = e - (lt ? 1.0f : 0.0f);
  x = x + tmp;
  float z  = x * x;
  float x3 = z * x;
  float y  =  7.0376836292e-2f * x + (-1.1514610310e-1f);
  float y1 = -1.2420140846e-1f * x +   1.4249322787e-1f;
  float y2 =  2.0000714765e-1f * x + (-2.4999993993e-1f);
  y  = y  * x +   1.1676998740e-1f;
  y1 = y1 * x + (-1.6668057665e-1f);
  y2 = y2 * x +   3.3333331174e-1f;
  y  = y * x3 + y1;
  y  = y * x3 + y2;
  y  = y * x3;
  y  = y + e * (-2.12194440e-4f);
  x  = x - 0.5f * z;
  x  = x + y;
  x  = x + e * 0.693359375f;
  return x;
}

__device__ __forceinline__ float sumsq_unfused(const float* v) {
  #pragma clang fp contract(off)
  float a = 0.0f;
  #pragma unroll
  for (int d = 0; d < 32; d++) a = a + v[d] * v[d];
  return a;
}

__device__ __forceinline__ void threefry2x32(uint32_t k0, uint32_t k1,
                                             uint32_t x0, uint32_t x1,
                                             uint32_t& o0, uint32_t& o1) {
  uint32_t ks2 = k0 ^ k1 ^ 0x1BD11BDAu;
  x0 += k0; x1 += k1;
#define TF_RND(r) { x0 += x1; x1 = (x1 << (r)) | (x1 >> (32 - (r))); x1 ^= x0; }
  TF_RND(13) TF_RND(15) TF_RND(26) TF_RND(6)
  x0 += k1; x1 += ks2 + 1u;
  TF_RND(17) TF_RND(29) TF_RND(16) TF_RND(24)
  x0 += ks2; x1 += k0 + 2u;
  TF_RND(13) TF_RND(15) TF_RND(26) TF_RND(6)
  x0 += k0; x1 += k1 + 3u;
  TF_RND(17) TF_RND(29) TF_RND(16) TF_RND(24)
  x0 += k1; x1 += ks2 + 4u;
  TF_RND(13) TF_RND(15) TF_RND(26) TF_RND(6)
  x0 += ks2; x1 += k0 + 5u;
#undef TF_RND
  o0 = x0; o1 = x1;
}

// EXACT gumbel (validated R2). Rare path only.
__device__ __forceinline__ float gumbel_from_bits(uint32_t bits) {
  uint32_t mant = bits >> 9;
  float f = __uint_as_float(0x3F800000u | mant) - 1.0f;
  float u = mant ? f : TINY_F;
  float t = -plog_xla(u);
  return -plog_xla(t);
}

// FAST gumbel via v_log_f32 (certified by margin).
__device__ __forceinline__ float gumbel_fast(uint32_t bits) {
  uint32_t mant = bits >> 9;
  float f = __uint_as_float(0x3F800000u | mant) - 1.0f;
  float u = mant ? f : TINY_F;
  float t = -(__log2f(u) * LN2F);
  return -(__log2f(t) * LN2F);
}

// Uniform load forced to SGPR.
__device__ __forceinline__ float uload(const float* p) {
  float v = *p;
  return __int_as_float(__builtin_amdgcn_readfirstlane(__float_as_int(v)));
}

// DPP pair-combine step for (best, second). Only lane 63's result is consumed;
// its combine chain reads only valid lanes (masked lanes fold to self, which
// can only inflate other lanes' "second" -> conservative, never wrong).
#define DPP_STEP(CTRL, RM)                                                     \
  {                                                                            \
    float nb = __int_as_float(__builtin_amdgcn_update_dpp(                     \
        __float_as_int(b1), __float_as_int(b1), (CTRL), (RM), 0xf, false));    \
    float ns = __int_as_float(__builtin_amdgcn_update_dpp(                     \
        __float_as_int(b2), __float_as_int(b2), (CTRL), (RM), 0xf, false));    \
    float lo = fminf(b1, nb);                                                  \
    b1 = fmaxf(b1, nb);                                                        \
    b2 = fmaxf(fmaxf(b2, ns), lo);                                             \
  }

__global__ __launch_bounds__(256, 8)
void mcq_fused(const float* __restrict__ x, const float* __restrict__ cb,
               float* __restrict__ sample, float* __restrict__ code,
               float* __restrict__ logit) {
  __shared__ float2 s_bs[GRP][4];                 // per-wave (best, second)
  __shared__ int    s_win[PPB];                   // winner k per pixel
  __shared__ unsigned long long s_scr[256];       // rare-path scratch

  const int t     = threadIdx.x;                  // k index
  const int lane  = t & 63, wv = t >> 6;
  const int pbase = blockIdx.x * PPB;             // 2048 blocks
  const int nm    = pbase >> 12;                  // uniform per block (PPB=128 | 4096)
  const int m     = nm & 3;

  // codebook row k=t -> REGISTERS (vector loads, once)
  const float* crow = cb + (size_t)m * (KK * DD) + (size_t)t * DD;
  float c[DD];
  #pragma unroll
  for (int j = 0; j < 8; j++) {
    float4 q = ((const float4*)crow)[j];
    c[4*j+0] = q.x; c[4*j+1] = q.y; c[4*j+2] = q.z; c[4*j+3] = q.w;
  }
  const float c2 = sumsq_unfused(c);              // validated unfused chain

  const float* xbase = x + (size_t)nm * 131072;   // + d*4096 + hw

  for (int g = 0; g < PPB / GRP; ++g) {
    float ph0, ph1, ph2, ph3;                     // named fast-phi per pixel

    // ---- A: compute phase (one pixel per macro expansion) ----
#define PIXEL(J, PH)                                                           \
    {                                                                          \
      const int pix = g * GRP + (J);                                           \
      const int gp  = pbase + pix;                                             \
      const int hw  = gp & 4095;                                               \
      float sx[32];                                                            \
      _Pragma("unroll")                                                        \
      for (int d = 0; d < 32; d++)                                             \
        sx[d] = uload(xbase + (size_t)d * 4096 + hw);                          \
      const float x2 = sumsq_unfused(sx);         /* validated unfused */      \
      float inter = 0.0f;                         /* validated fused asc */    \
      _Pragma("unroll")                                                        \
      for (int d = 0; d < 32; d++)                                             \
        inter = __builtin_fmaf(sx[d], c[d], inter);                            \
      float dist = (x2 + c2) - 2.0f * inter;                                   \
      float L = __log2f(dist) * LN2F;                                          \
      logit[((size_t)gp << 8) + t] = L;                                        \
      uint32_t v0, v1;                                                         \
      threefry2x32(0u, 42u, 0u, ((uint32_t)gp << 8) | (uint32_t)t, v0, v1);    \
      PH = gumbel_fast(v0 ^ v1) + L;                                           \
      /* wave top-2 via DPP (VALU pipe) */                                     \
      float b1 = PH, b2 = -__builtin_inff();                                   \
      DPP_STEP(0x111, 0xf)   /* row_shr:1  */                                  \
      DPP_STEP(0x112, 0xf)   /* row_shr:2  */                                  \
      DPP_STEP(0x114, 0xf)   /* row_shr:4  */                                  \
      DPP_STEP(0x118, 0xf)   /* row_shr:8  */                                  \
      DPP_STEP(0x142, 0xa)   /* bcast15 -> rows 1,3 */                         \
      DPP_STEP(0x143, 0xc)   /* bcast31 -> rows 2,3 */                         \
      if (lane == 63) s_bs[(J)][wv] = make_float2(b1, b2);                     \
    }

    PIXEL(0, ph0)
    PIXEL(1, ph1)
    PIXEL(2, ph2)
    PIXEL(3, ph3)
#undef PIXEL

    __syncthreads();   // B1: s_bs visible

    // ---- B: finalize (uniform per block) ----
    unsigned int uflag = 0;
#define FINAL(J, PH)                                                           \
    {                                                                          \
      const int pix = g * GRP + (J);                                           \
      float2 q0 = s_bs[(J)][0], q1 = s_bs[(J)][1];                             \
      float2 q2 = s_bs[(J)][2], q3 = s_bs[(J)][3];                             \
      float P1 = q0.x; int winwv = 0;                                          \
      if (q1.x > P1) { P1 = q1.x; winwv = 1; }                                 \
      if (q2.x > P1) { P1 = q2.x; winwv = 2; }                                 \
      if (q3.x > P1) { P1 = q3.x; winwv = 3; }                                 \
      float P2 = fmaxf(fmaxf(q0.y, q1.y), fmaxf(q2.y, q3.y));                  \
      if (winwv != 0) P2 = fmaxf(P2, q0.x);                                    \
      if (winwv != 1) P2 = fmaxf(P2, q1.x);                                    \
      if (winwv != 2) P2 = fmaxf(P2, q2.x);                                    \
      if (winwv != 3) P2 = fmaxf(P2, q3.x);                                    \
      if (wv == winwv) {                                                       \
        unsigned long long mk = __ballot((PH) == P1);                          \
        if (lane == 0) s_win[pix] = (winwv << 6) + (__ffsll(mk) - 1);          \
      }                                                                        \
      if (!(P1 - P2 > MARGIN)) uflag |= (1u << (J));                           \
    }

    FINAL(0, ph0)
    FINAL(1, ph1)
    FINAL(2, ph2)
    FINAL(3, ph3)
#undef FINAL

    __syncthreads();   // B2: s_win visible; s_bs safe for reuse

    // ---- C: rare exact fallback (fully validated arithmetic) ----
    if (__builtin_expect(uflag != 0, 0)) {
      for (int j = 0; j < GRP; ++j) {
        if (!(uflag & (1u << j))) continue;
        const int pix = g * GRP + j;
        const int gp  = pbase + pix;
        const int hw  = gp & 4095;
        float inter = 0.0f, x2r;
        {
          float sxr[32];
          #pragma unroll
          for (int d = 0; d < 32; d++)
            sxr[d] = uload(xbase + (size_t)d * 4096 + hw);
          x2r = sumsq_unfused(sxr);
          #pragma unroll
          for (int d = 0; d < 32; d++)
            inter = __builtin_fmaf(sxr[d], c[d], inter);
        }
        float dist = (x2r + c2) - 2.0f * inter;
        float Le = plog_xla(dist);
        uint32_t v0, v1;
        threefry2x32(0u, 42u, 0u, ((uint32_t)gp << 8) | (uint32_t)t, v0, v1);
        float phe = gumbel_from_bits(v0 ^ v1) + Le;
        uint32_t pb = __float_as_uint(phe);
        pb ^= (uint32_t)(((int32_t)pb) >> 31) | 0x80000000u;   // order-preserving
        unsigned long long packed =
            ((unsigned long long)pb << 32) | (unsigned long long)(255 - t);
        s_scr[t] = packed;
        __syncthreads();
        for (int st = 128; st > 0; st >>= 1) {
          if (t < st) {
            unsigned long long o = s_scr[t + st];
            if (o > s_scr[t]) s_scr[t] = o;
          }
          __syncthreads();
        }
        if (t == 0) s_win[pix] = 255 - (int)(s_scr[0] & 0xFFu);
        __syncthreads();
      }
    }

    // ---- D: sample writes (coalesced 4B per thread) ----
    #pragma unroll
    for (int j = 0; j < GRP; ++j) {
      const int pix = g * GRP + j;
      const int gp  = pbase + pix;
      const int w   = s_win[pix];
      sample[((size_t)gp << 8) + t] = (t == w) ? 1.0f : 0.0f;
    }
  }

  __syncthreads();
  if (t < PPB) code[pbase + t] = (float)s_win[t];
}

extern "C" void kernel_launch(void* const* d_in, const int* in_sizes, int n_in,
                              void* d_out, int out_size, void* d_ws, size_t ws_size,
                              hipStream_t stream) {
  const float* x  = (const float*)d_in[0];
  const float* cb = (const float*)d_in[1];

  float* out_f  = (float*)d_out;
  float* sample = out_f;                       // 67108864
  float* code   = out_f + 67108864;            // 262144 (as float)
  float* logit  = out_f + 67108864 + 262144;   // 67108864

  mcq_fused<<<262144 / PPB, 256, 0, stream>>>(x, cb, sample, code, logit);
}

// Round 12
// 378.856 us; speedup vs baseline: 1.7585x; 1.7585x over previous
//
#include <hip/hip_runtime.h>
#include <stdint.h>

// N=16, M=4, D=32, K=256, H=64, W=64 ; P = 262144 pixels
// outputs (concat, read back as f32): sample (P*256), code (P, as float), logit (P*256)
// d_ws: uint2[2][P] = (exact phi bits, winner k) per (half, pixel)
// mcq_main: thread = pixel-pair, block = 512 pixel-halves (2 px/thread), half-k in LDS.

#define TINY_F 1.17549435082228750797e-38f
#define LN2F   0.69314718055994530942f
#define MARGIN 2.0e-4f

constexpr int KK   = 256;
constexpr int DD   = 32;
constexpr int HALF = 128;
constexpr int P_TOT = 262144;

// XLA:CPU vectorized log (GenerateVF32Log / Eigen plog), UNFUSED mul+add.
// Bit-exactness validated round 2 (code absmax == 0). Exact path only.
__device__ __forceinline__ float plog_xla(float xin) {
  #pragma clang fp contract(off)
  uint32_t ix = __float_as_uint(xin);
  int e_i = (int)(ix >> 23) - 126;
  float x = __uint_as_float((ix & 0x007FFFFFu) | 0x3F000000u);
  float e = (float)e_i;
  bool lt = x < 0.707106781186547524f;
  float tmp = lt ? x : 0.0f;
  x = x - 1.0f;
  e = e - (lt ? 1.0f : 0.0f);
  x = x + tmp;
  float z  = x * x;
  float x3 = z * x;
  float y  =  7.0376836292e-2f * x + (-1.1514610310e-1f);
  float y1 = -1.2420140846e-1f * x +   1.4249322787e-1f;
  float y2 =  2.0000714765e-1f * x + (-2.4999993993e-1f);
  y  = y  * x +   1.1676998740e-1f;
  y1 = y1 * x + (-1.6668057665e-1f);
  y2 = y2 * x +   3.3333331174e-1f;
  y  = y * x3 + y1;
  y  = y * x3 + y2;
  y  = y * x3;
  y  = y + e * (-2.12194440e-4f);
  x  = x - 0.5f * z;
  x  = x + y;
  x  = x + e * 0.693359375f;
  return x;
}

__device__ __forceinline__ float sumsq_unfused(const float* v) {
  #pragma clang fp contract(off)
  float a = 0.0f;
  #pragma unroll
  for (int d = 0; d < 32; d++) a = a + v[d] * v[d];
  return a;
}

__device__ __forceinline__ void threefry2x32(uint32_t k0, uint32_t k1,
                                             uint32_t x0, uint32_t x1,
                                             uint32_t& o0, uint32_t& o1) {
  uint32_t ks2 = k0 ^ k1 ^ 0x1BD11BDAu;
  x0 += k0; x1 += k1;
#define TF_RND(r) { x0 += x1; x1 = (x1 << (r)) | (x1 >> (32 - (r))); x1 ^= x0; }
  TF_RND(13) TF_RND(15) TF_RND(26) TF_RND(6)
  x0 += k1; x1 += ks2 + 1u;
  TF_RND(17) TF_RND(29) TF_RND(16) TF_RND(24)
  x0 += ks2; x1 += k0 + 2u;
  TF_RND(13) TF_RND(15) TF_RND(26) TF_RND(6)
  x0 += k0; x1 += k1 + 3u;
  TF_RND(17) TF_RND(29) TF_RND(16) TF_RND(24)
  x0 += k1; x1 += ks2 + 4u;
  TF_RND(13) TF_RND(15) TF_RND(26) TF_RND(6)
  x0 += ks2; x1 += k0 + 5u;
#undef TF_RND
  o0 = x0; o1 = x1;
}

// EXACT gumbel (validated R2).
__device__ __forceinline__ float gumbel_from_bits(uint32_t bits) {
  uint32_t mant = bits >> 9;
  float f = __uint_as_float(0x3F800000u | mant) - 1.0f;
  float u = mant ? f : TINY_F;
  float t = -plog_xla(u);
  return -plog_xla(t);
}

// FAST gumbel via v_log_f32 (scan only; certified by margin).
__device__ __forceinline__ float gumbel_fast(uint32_t bits) {
  uint32_t mant = bits >> 9;
  float f = __uint_as_float(0x3F800000u | mant) - 1.0f;
  float u = mant ? f : TINY_F;
  float t = -(__log2f(u) * LN2F);
  return -(__log2f(t) * LN2F);
}

// exact phi for local row KL with x-vector XV (all-validated chains)
#define EXACT_PHI(OUT, KL, XV, X2, LB)                                         \
  {                                                                            \
    const int _kl = (KL);                                                      \
    const float4* _rp = (const float4*)(s_cb2 + (size_t)_kl * DD);             \
    float _in = 0.0f;                                                          \
    _Pragma("unroll")                                                          \
    for (int _j = 0; _j < 8; _j++) {                                           \
      float4 _q = _rp[_j];                                                     \
      _in = __builtin_fmaf(XV[4*_j+0], _q.x, _in);                             \
      _in = __builtin_fmaf(XV[4*_j+1], _q.y, _in);                             \
      _in = __builtin_fmaf(XV[4*_j+2], _q.z, _in);                             \
      _in = __builtin_fmaf(XV[4*_j+3], _q.w, _in);                             \
    }                                                                          \
    float _d = ((X2) + s_c2h[_kl]) - 2.0f * _in;                               \
    float _L = plog_xla(_d);                                                   \
    uint32_t _v0, _v1;                                                         \
    threefry2x32(0u, 42u, 0u, (LB) + (uint32_t)_kl, _v0, _v1);                 \
    OUT = gumbel_from_bits(_v0 ^ _v1) + _L;                                    \
  }

#define TRACK(P, KL, BEST, SEC, THI, I1, I2)                                   \
  if ((P) > BEST) { THI = SEC; SEC = BEST; I2 = I1; BEST = (P); I1 = (KL); }   \
  else if ((P) > SEC) { THI = SEC; SEC = (P); I2 = (KL); }                     \
  else if ((P) > THI) THI = (P);

// resolve one pixel's half-winner from its top-3 fast scores (validated R10 logic)
#define RESOLVE(BEST, SEC, THI, I1, I2, XV, X2, LB, WOUT, FOUT)                \
  {                                                                            \
    if (BEST - SEC > MARGIN) {                                                 \
      WOUT = I1;                                                               \
      EXACT_PHI(FOUT, WOUT, XV, X2, LB)                                        \
    } else if (BEST - THI > MARGIN) {                                          \
      int _ka = I1 < I2 ? I1 : I2;                                             \
      int _kb = I1 < I2 ? I2 : I1;                                             \
      float _fa, _fb;                                                          \
      EXACT_PHI(_fa, _ka, XV, X2, LB)                                          \
      EXACT_PHI(_fb, _kb, XV, X2, LB)                                          \
      if (_fb > _fa) { WOUT = _kb; FOUT = _fb; }                               \
      else           { WOUT = _ka; FOUT = _fa; }                               \
    } else {                                                                   \
      float _bb = -__builtin_inff(); int _wbb = 0;                             \
      for (int _k2 = 0; _k2 < HALF; _k2++) {                                   \
        float _ph;                                                             \
        EXACT_PHI(_ph, _k2, XV, X2, LB)                                        \
        if (_ph > _bb) { _bb = _ph; _wbb = _k2; }                              \
      }                                                                        \
      WOUT = _wbb; FOUT = _bb;                                                 \
    }                                                                          \
  }

__global__ __launch_bounds__(256, 4)
void mcq_main(const float* __restrict__ x, const float* __restrict__ cb,
              float* __restrict__ logit, uint2* __restrict__ ws) {
  __shared__ __align__(16) float s_cb2[HALF * DD];  // 16 KB
  __shared__ __align__(16) float s_c2h[HALF];       // 512 B

  const int t   = threadIdx.x;
  const int bid = blockIdx.x;          // 1024 blocks = (group g, half h)
  const int g   = bid >> 1;
  const int h   = bid & 1;
  const int pbase = g << 9;            // 512 pixels per group
  const int nm  = pbase >> 12;         // uniform (512 | 4096)
  const int m   = nm & 3;
  const int gp0 = pbase + t;           // pixel A
  const int gp1 = pbase + 256 + t;     // pixel B
  const int hw0 = gp0 & 4095;
  const int hw1 = gp1 & 4095;

  const float* cbm = cb + (size_t)m * (KK * DD) + (size_t)h * (HALF * DD);

  // stage half codebook -> LDS (1024 float4, 4/thread)
  {
    const float4* src = (const float4*)cbm;
    float4* dst = (float4*)s_cb2;
    #pragma unroll
    for (int i = 0; i < 4; i++)
      dst[t + 256 * i] = src[t + 256 * i];
  }

  // x[d] for both pixels -> VGPRs (coalesced across threads per d)
  const float* xb = x + (size_t)nm * 131072;
  float xv0[DD], xv1[DD];
  #pragma unroll
  for (int d = 0; d < DD; d++) xv0[d] = xb[(size_t)d * 4096 + hw0];
  #pragma unroll
  for (int d = 0; d < DD; d++) xv1[d] = xb[(size_t)d * 4096 + hw1];

  const float x2_0 = sumsq_unfused(xv0);
  const float x2_1 = sumsq_unfused(xv1);

  // c2 for local rows (validated unfused chain)
  if (t < HALF) {
    const float4* rp = (const float4*)(cbm + t * DD);
    float cr[DD];
    #pragma unroll
    for (int j = 0; j < 8; j++) {
      float4 q = rp[j];
      cr[4*j+0] = q.x; cr[4*j+1] = q.y; cr[4*j+2] = q.z; cr[4*j+3] = q.w;
    }
    s_c2h[t] = sumsq_unfused(cr);
  }
  __syncthreads();

  float* lrow0 = logit + ((size_t)gp0 << 8) + h * HALF;
  float* lrow1 = logit + ((size_t)gp1 << 8) + h * HALF;
  const uint32_t lbase0 = ((uint32_t)gp0 << 8) + (uint32_t)(h * HALF);
  const uint32_t lbase1 = ((uint32_t)gp1 << 8) + (uint32_t)(h * HALF);

  float bestA = -__builtin_inff(), secA = -__builtin_inff(), thiA = -__builtin_inff();
  float bestB = -__builtin_inff(), secB = -__builtin_inff(), thiB = -__builtin_inff();
  int biA1 = 0, biA2 = 0, biB1 = 0, biB2 = 0;

  // one k: one row read (8 x b128 broadcast) feeds BOTH pixels' fused chains
#define K1(KK_IDX, LA, LB)                                                     \
  {                                                                            \
    const int kl = kc + (KK_IDX);                                              \
    const float c2k = s_c2h[kl];                                               \
    const float4* rp = (const float4*)(s_cb2 + (size_t)kl * DD);               \
    float i0 = 0.0f, i1 = 0.0f;                                                \
    _Pragma("unroll")                                                          \
    for (int j = 0; j < 8; j++) {                                              \
      float4 q = rp[j];                                                        \
      i0 = __builtin_fmaf(xv0[4*j+0], q.x, i0);                                \
      i1 = __builtin_fmaf(xv1[4*j+0], q.x, i1);                                \
      i0 = __builtin_fmaf(xv0[4*j+1], q.y, i0);                                \
      i1 = __builtin_fmaf(xv1[4*j+1], q.y, i1);                                \
      i0 = __builtin_fmaf(xv0[4*j+2], q.z, i0);                                \
      i1 = __builtin_fmaf(xv1[4*j+2], q.z, i1);                                \
      i0 = __builtin_fmaf(xv0[4*j+3], q.w, i0);                                \
      i1 = __builtin_fmaf(xv1[4*j+3], q.w, i1);                                \
    }                                                                          \
    float d0 = (x2_0 + c2k) - 2.0f * i0;                                       \
    float d1 = (x2_1 + c2k) - 2.0f * i1;                                       \
    LA = __log2f(d0) * LN2F;                                                   \
    LB = __log2f(d1) * LN2F;                                                   \
    uint32_t a0, a1, b0, b1;                                                   \
    threefry2x32(0u, 42u, 0u, lbase0 + (uint32_t)kl, a0, a1);                  \
    threefry2x32(0u, 42u, 0u, lbase1 + (uint32_t)kl, b0, b1);                  \
    float pA = gumbel_fast(a0 ^ a1) + LA;                                      \
    float pB = gumbel_fast(b0 ^ b1) + LB;                                      \
    TRACK(pA, kl, bestA, secA, thiA, biA1, biA2)                               \
    TRACK(pB, kl, bestB, secB, thiB, biB1, biB2)                               \
  }

  #pragma unroll 1
  for (int kc = 0; kc < HALF; kc += 8) {
    float A0,A1,A2,A3,A4,A5,A6,A7;    // named regs only (no indexed arrays)
    float B0,B1,B2,B3,B4,B5,B6,B7;
    K1(0, A0, B0)
    K1(1, A1, B1)
    K1(2, A2, B2)
    K1(3, A3, B3)
    K1(4, A4, B4)
    K1(5, A5, B5)
    K1(6, A6, B6)
    K1(7, A7, B7)
    float4* d0p = (float4*)(lrow0 + kc);    // 32B bursts per pixel
    d0p[0] = make_float4(A0, A1, A2, A3);
    d0p[1] = make_float4(A4, A5, A6, A7);
    float4* d1p = (float4*)(lrow1 + kc);
    d1p[0] = make_float4(B0, B1, B2, B3);
    d1p[1] = make_float4(B4, B5, B6, B7);
  }
#undef K1

  // resolve both half-winners with exact phi (validated chains)
  int wA, wB; float fA, fB;
  RESOLVE(bestA, secA, thiA, biA1, biA2, xv0, x2_0, lbase0, wA, fA)
  RESOLVE(bestB, secB, thiB, biB1, biB2, xv1, x2_1, lbase1, wB, fB)

  ws[(h << 18) + gp0] = make_uint2(__float_as_uint(fA), (uint32_t)(wA + h * HALF));
  ws[(h << 18) + gp1] = make_uint2(__float_as_uint(fB), (uint32_t)(wB + h * HALF));
}

__global__ __launch_bounds__(256)
void mcq_combine(const uint2* __restrict__ ws, float* __restrict__ sample,
                 float* __restrict__ code) {
  __shared__ int s_wb[256];
  const int t = threadIdx.x;
  const int b = blockIdx.x;          // 1024 blocks x 256 pixels
  const int gp = (b << 8) + t;

  uint2 a = ws[gp];
  uint2 c = ws[P_TOT + gp];
  float fa = __uint_as_float(a.x);
  float fc = __uint_as_float(c.x);
  // exact compare; tie -> half 0 (smaller k, first occurrence)
  int win = (fc > fa) ? (int)c.y : (int)a.y;

  code[gp] = (float)win;
  s_wb[t] = win;
  __syncthreads();

  const int lane = t & 63, wv = t >> 6;
  const int pbase = b << 8;
  const int k0 = lane << 2;
  for (int r = wv * 64; r < (wv + 1) * 64; r++) {
    const int w = s_wb[r];
    float4 v;
    v.x = (w == k0 + 0) ? 1.0f : 0.0f;
    v.y = (w == k0 + 1) ? 1.0f : 0.0f;
    v.z = (w == k0 + 2) ? 1.0f : 0.0f;
    v.w = (w == k0 + 3) ? 1.0f : 0.0f;
    ((float4*)(sample + (((size_t)(pbase + r)) << 8)))[lane] = v;
  }
}

extern "C" void kernel_launch(void* const* d_in, const int* in_sizes, int n_in,
                              void* d_out, int out_size, void* d_ws, size_t ws_size,
                              hipStream_t stream) {
  const float* x  = (const float*)d_in[0];
  const float* cb = (const float*)d_in[1];

  float* out_f  = (float*)d_out;
  float* sample = out_f;                       // 67108864
  float* code   = out_f + 67108864;            // 262144 (as float)
  float* logit  = out_f + 67108864 + 262144;   // 67108864
  uint2* ws     = (uint2*)d_ws;                // 2 * 262144 * 8B = 4 MB

  mcq_main<<<1024, 256, 0, stream>>>(x, cb, logit, ws);
  mcq_combine<<<1024, 256, 0, stream>>>(ws, sample, code);
}